// Round 17
// baseline (185.888 us; speedup 1.0000x reference)
//
#include <hip/hip_runtime.h>
#include <math.h>

// VQ-VAE eval forward. z_e [32,256,32,32] fp32, E [4096,256] fp32.
// N = 32768 queries, K = 4096 codes, C = 256.
// Round 17: NO-LDS screen -- B-operands loaded directly from the 2MB packed
// E-image (L2-resident per XCD; Common-mistake #7 / m169 precedent). Image
// layout [chunk64][j=0..31][code64] granules: one b128 per (ks,t) fragment,
// coalesced 4x256B per wave, compile-time offsets. Zero barriers/LDS/staging.
// A = fp16(z*8), B = fp16(-e*256), C-init = en*1024 -> acc = d*1024 direct.
// Packed-int top-3 keys (med3 insert), WGAP=52, fp64 cand3/messy anchor.

#define WGAP 52   // quantized-distance window (units of 1/1024)

using half8 = __attribute__((ext_vector_type(8))) _Float16;
using f32x4 = __attribute__((ext_vector_type(4))) float;

__device__ __forceinline__ bool lexlt64(double v, int x, double ov, int ox) {
  return (v < ov) || (v == ov && x < ox);
}

__device__ __forceinline__ int med3i(int a, int b, int c) {
  int d;
  asm("v_med3_i32 %0, %1, %2, %3" : "=v"(d) : "v"(a), "v"(b), "v"(c));
  return d;
}

// insert key into sorted triple (a0<=a1<=a2): 4 VALU ops via med3
__device__ __forceinline__ void ins3k(int key, int& a0, int& a1, int& a2) {
  const int n2 = min(a2, max(key, a1));
  const int n1 = med3i(key, a0, a1);
  a0 = min(key, a0);
  a1 = n1;
  a2 = n2;
}

// merge two sorted triples -> smallest 3 of union: 7 min/max ops
__device__ __forceinline__ void mrg3k(int& a0, int& a1, int& a2,
                                      int b0, int b1, int b2) {
  const int c0 = min(a0, b0);
  const int x = max(a0, b0);
  const int y = min(a1, b1);
  const int c1 = min(x, y);
  const int z = max(x, y);
  const int ww = min(a2, b2);
  const int c2 = min(z, ww);
  a0 = c0; a1 = c1; a2 = c2;
}

// ---------------- K1: E -> NEGATED fp16(x256) [chunk][j][code] image + enorm*1024 ----------------
// granule(16B) g = (code>>6)*2048 + j*64 + (code&63), j = k-octet 0..31.
// Screen reads (ch, ks, tile t, lane l): byte = ch*32768 + ks*4096
//   + (l>>4)*1024 + t*256 + (l&15)*16  -> contiguous 256B per 16-lane group.
// Also zeroes used[] and scalar accumulators (replay-safe).
__global__ __launch_bounds__(256) void vq_prep(const float* __restrict__ E,
                                               uint4* __restrict__ Epk,
                                               float* __restrict__ en1024,
                                               int* __restrict__ used,
                                               double* __restrict__ lossSum,
                                               int* __restrict__ candCount,
                                               int* __restrict__ messyCount) {
  const int t = blockIdx.x * 256 + threadIdx.x;   // 131072 = 4096 codes x 32 octets
  if (t < 4096) used[t] = 0;
  if (t == 4096) *lossSum = 0.0;
  if (t == 4097) *candCount = 0;
  if (t == 4098) *messyCount = 0;
  const int code = t >> 5, j = t & 31;
  const float* src = E + (size_t)code * 256 + j * 8;
  const float4 v0 = *(const float4*)(src);
  const float4 v1 = *(const float4*)(src + 4);
  float zv[8] = {v0.x, v0.y, v0.z, v0.w, v1.x, v1.y, v1.z, v1.w};
  union { half8 h; uint4 u; } pk;
  float s = 0.f;
#pragma unroll
  for (int e = 0; e < 8; ++e) {
    const float z = zv[e];
    s = fmaf(z, z, s);
    pk.h[e] = (_Float16)(z * -256.0f);   // negated image
  }
  const size_t g = (size_t)(code >> 6) * 2048 + j * 64 + (code & 63);
  Epk[g] = pk.u;
#pragma unroll
  for (int off = 1; off < 32; off <<= 1) s += __shfl_xor(s, off);
  if (j == 0) en1024[code] = s * 1024.0f;
}

// ---------------- K2: fp16 MFMA screen, direct-from-L2 B-operands ----------------
// grid 768 = 256 query-groups (128 q) x 3 code-parts (22/21/21 chunks of 64).
// 4 waves x 32 q (2 tiles); NO LDS, NO barriers -- waves fully independent.
// XCD swizzle: bid = (qg%8) + 8*(part + 3*(qg/8)) -> one qg per XCD
// (Epk + Z stay XCD-L2-local).
__global__ __launch_bounds__(256, 3) void vq_screen(
    const float* __restrict__ Z, const char* __restrict__ Epk,
    const float* __restrict__ en1024,
    int* __restrict__ pk0, int* __restrict__ pk1, int* __restrict__ pk2) {
  const int tid = threadIdx.x;
  const int w = tid >> 6, l = tid & 63;
  const int xcd = blockIdx.x & 7, inner = blockIdx.x >> 3;
  const int part = inner % 3;
  const int qg = (inner / 3) * 8 + xcd;
  const int chs = part * 21 + (part > 0 ? 1 : 0);     // {0, 22, 43}
  const int che = chs + (part == 0 ? 22 : 21);        // {22, 43, 64}
  const int qbase = qg * 128;
  const int b = qbase >> 10;
  const int hwq = (qbase & 1023) + w * 32 + (l & 15);

  // A-frags: fp16(z*8), 2 query-tiles x K=256
  const float* Zq = Z + (size_t)b * 262144 + hwq;
  half8 ah[2][8];
#pragma unroll
  for (int u = 0; u < 2; ++u)
#pragma unroll
    for (int ks = 0; ks < 8; ++ks) {
      const int c0 = ks * 32 + (l >> 4) * 8;
#pragma unroll
      for (int e = 0; e < 8; ++e)
        ah[u][ks][e] = (_Float16)(Zq[u * 16 + ((size_t)(c0 + e) << 10)] * 8.0f);
    }

  // per-lane image base (j-group from l>>4, code-in-chunk from l&15)
  const char* Eb = Epk + (l >> 4) * 1024 + (l & 15) * 16;

  int k0[2][4], k1[2][4], k2[2][4];
#pragma unroll
  for (int u = 0; u < 2; ++u)
#pragma unroll
    for (int r = 0; r < 4; ++r) {
      k0[u][r] = 0x7fffffff; k1[u][r] = 0x7fffffff; k2[u][r] = 0x7fffffff;
    }

  for (int ch = chs; ch < che; ++ch) {
    const int cb = ch * 64;
    const char* Cb = Eb + (size_t)ch * 32768;
    f32x4 acc[2][4];
#pragma unroll
    for (int t = 0; t < 4; ++t) {
      const float en = en1024[cb + t * 16 + (l & 15)];
      acc[0][t] = (f32x4){en, en, en, en};
      acc[1][t] = (f32x4){en, en, en, en};
    }

    __builtin_amdgcn_s_setprio(1);
#pragma unroll
    for (int ks = 0; ks < 8; ++ks) {
      const char* p = Cb + ks * 4096;
      const half8 e0 = *(const half8*)(p);
      const half8 e1 = *(const half8*)(p + 256);
      const half8 e2 = *(const half8*)(p + 512);
      const half8 e3 = *(const half8*)(p + 768);
      acc[0][0] = __builtin_amdgcn_mfma_f32_16x16x32_f16(ah[0][ks], e0, acc[0][0], 0, 0, 0);
      acc[1][0] = __builtin_amdgcn_mfma_f32_16x16x32_f16(ah[1][ks], e0, acc[1][0], 0, 0, 0);
      acc[0][1] = __builtin_amdgcn_mfma_f32_16x16x32_f16(ah[0][ks], e1, acc[0][1], 0, 0, 0);
      acc[1][1] = __builtin_amdgcn_mfma_f32_16x16x32_f16(ah[1][ks], e1, acc[1][1], 0, 0, 0);
      acc[0][2] = __builtin_amdgcn_mfma_f32_16x16x32_f16(ah[0][ks], e2, acc[0][2], 0, 0, 0);
      acc[1][2] = __builtin_amdgcn_mfma_f32_16x16x32_f16(ah[1][ks], e2, acc[1][2], 0, 0, 0);
      acc[0][3] = __builtin_amdgcn_mfma_f32_16x16x32_f16(ah[0][ks], e3, acc[0][3], 0, 0, 0);
      acc[1][3] = __builtin_amdgcn_mfma_f32_16x16x32_f16(ah[1][ks], e3, acc[1][3], 0, 0, 0);
    }
    __builtin_amdgcn_s_setprio(0);

    // epilogue: acc IS d*1024; pack key; 4-op insert
#pragma unroll
    for (int t = 0; t < 4; ++t) {
      const int code = cb + t * 16 + (l & 15);
#pragma unroll
      for (int u = 0; u < 2; ++u)
#pragma unroll
        for (int r = 0; r < 4; ++r) {
          const int di = (int)acc[u][t][r];             // trunc: monotone
          const int key = (int)(((unsigned)di << 12) + (unsigned)code);
          ins3k(key, k0[u][r], k1[u][r], k2[u][r]);
        }
    }
  }

  // cross-lane top-3 merge over the 16 lanes sharing each row-group
#pragma unroll
  for (int mask = 1; mask <= 8; mask <<= 1) {
#pragma unroll
    for (int u = 0; u < 2; ++u)
#pragma unroll
      for (int r = 0; r < 4; ++r) {
        const int o0 = __shfl_xor(k0[u][r], mask);
        const int o1 = __shfl_xor(k1[u][r], mask);
        const int o2 = __shfl_xor(k2[u][r], mask);
        mrg3k(k0[u][r], k1[u][r], k2[u][r], o0, o1, o2);
      }
  }
  if ((l & 15) == 0) {
#pragma unroll
    for (int u = 0; u < 2; ++u)
#pragma unroll
      for (int r = 0; r < 4; ++r) {
        const int n = qbase + w * 32 + u * 16 + (l >> 4) * 4 + r;
        const int o = part * 32768 + n;
        pk0[o] = k0[u][r]; pk1[o] = k1[u][r]; pk2[o] = k2[u][r];
      }
  }
}

// ---------------- K3: merge 3 parts, classify ----------------
__global__ __launch_bounds__(256) void vq_merge(
    const int* __restrict__ pk0, const int* __restrict__ pk1,
    const int* __restrict__ pk2, int* __restrict__ idxOut,
    int* __restrict__ cand, int* __restrict__ candCount,
    int* __restrict__ messy, int* __restrict__ messyCount,
    int* __restrict__ pi0, int* __restrict__ pi1, int* __restrict__ pi2) {
  const int n = blockIdx.x * 256 + threadIdx.x;
  int a0 = pk0[n], a1 = pk1[n], a2 = pk2[n];
#pragma unroll
  for (int q = 1; q < 3; ++q) {
    const int o = q * 32768 + n;
    mrg3k(a0, a1, a2, pk0[o], pk1[o], pk2[o]);
  }
  const int x0 = a0 & 0xfff;
  idxOut[n] = x0;                       // final unless flagged
  const int d0 = a0 >> 12, d1 = a1 >> 12, d2 = a2 >> 12;
  if (d1 - d0 < WGAP) {
    if (d2 - d0 < WGAP) {
      const int p = atomicAdd(messyCount, 1);
      if (p < 4096) messy[p] = n;
    } else {
      const int p = atomicAdd(candCount, 1);
      cand[p] = n;
      pi0[n] = x0; pi1[n] = a1 & 0xfff; pi2[n] = a2 & 0xfff;
    }
  }
}

// ---------------- K4: fused exact resolution (block-range split, no fences) ----
// Blocks [0,256): fp64 3-way compare for cand queries (wave per query).
// Blocks [256,768): fp64 full-row partial argmin for messy queries.
__global__ __launch_bounds__(256) void vq_exact(
    const float* __restrict__ Z, const float* __restrict__ E,
    const int* __restrict__ pi0, const int* __restrict__ pi1,
    const int* __restrict__ pi2, const int* __restrict__ cand,
    const int* __restrict__ candCount, const int* __restrict__ messy,
    const int* __restrict__ messyCount, double* __restrict__ parv,
    int* __restrict__ parx, int* __restrict__ idxOut) {
  __shared__ float zs[4][256];
  __shared__ double rv[4][256];
  __shared__ int ri[4][256];
  const int t = threadIdx.x;
  const int w = t >> 6, l = t & 63;

  if (blockIdx.x < 256) {
    // ---- cand3: one wave per query, stride 1024 ----
    const int cnt = *candCount;
    for (int j = blockIdx.x * 4 + w; j < cnt; j += 1024) {
      const int n = cand[j];
      const int b = n >> 10, hw = n & 1023;
      const int ca = pi0[n], cbn = pi1[n], cc = pi2[n];
      float z4[4];
#pragma unroll
      for (int i = 0; i < 4; ++i)
        z4[i] = Z[(size_t)b * 262144 + ((size_t)(l * 4 + i) << 10) + hw];
      const float4 e0 = *(const float4*)(E + (size_t)ca * 256 + l * 4);
      const float4 e1 = *(const float4*)(E + (size_t)cbn * 256 + l * 4);
      const float4 e2 = *(const float4*)(E + (size_t)cc * 256 + l * 4);
      double d0 = 0, d1 = 0, d2 = 0;
      const float* p0 = (const float*)&e0;
      const float* p1 = (const float*)&e1;
      const float* p2 = (const float*)&e2;
#pragma unroll
      for (int i = 0; i < 4; ++i) {
        const double f0 = (double)z4[i] - (double)p0[i];
        const double f1 = (double)z4[i] - (double)p1[i];
        const double f2 = (double)z4[i] - (double)p2[i];
        d0 = fma(f0, f0, d0);
        d1 = fma(f1, f1, d1);
        d2 = fma(f2, f2, d2);
      }
#pragma unroll
      for (int off = 32; off > 0; off >>= 1) {
        d0 += __shfl_down(d0, off);
        d1 += __shfl_down(d1, off);
        d2 += __shfl_down(d2, off);
      }
      if (l == 0) {
        double bv = d0; int bx = ca;
        if (lexlt64(d1, cbn, bv, bx)) { bv = d1; bx = cbn; }
        if (lexlt64(d2, cc, bv, bx)) { bv = d2; bx = cc; }
        idxOut[n] = bx;
      }
    }
    return;
  }

  // ---- messy1: 512 blocks, chunked fp64 full-row partial argmin ----
  const int cnt0 = *messyCount;
  const int cnt = cnt0 > 4096 ? 4096 : cnt0;
  const int jobs = ((cnt + 3) >> 2) * 16;
  for (int job = blockIdx.x - 256; job < jobs; job += 512) {
    const int grp = job >> 4, chunk = job & 15;
    __syncthreads();
    {
      const int q = t >> 6, lq = t & 63;
      const int mi = grp * 4 + q;
      const int n = messy[mi < cnt ? mi : grp * 4];
      const int b = n >> 10, hw = n & 1023;
#pragma unroll
      for (int i = 0; i < 4; ++i)
        zs[q][lq * 4 + i] =
            Z[(size_t)b * 262144 + ((size_t)(lq * 4 + i) << 10) + hw];
    }
    __syncthreads();
    const int code = chunk * 256 + t;
    const float* er = E + (size_t)code * 256;
    double s0 = 0, s1 = 0, s2 = 0, s3 = 0;
    for (int c = 0; c < 256; ++c) {
      const double ec = (double)er[c];
      const double f0 = (double)zs[0][c] - ec;
      const double f1 = (double)zs[1][c] - ec;
      const double f2 = (double)zs[2][c] - ec;
      const double f3 = (double)zs[3][c] - ec;
      s0 = fma(f0, f0, s0);
      s1 = fma(f1, f1, s1);
      s2 = fma(f2, f2, s2);
      s3 = fma(f3, f3, s3);
    }
    rv[0][t] = s0; rv[1][t] = s1; rv[2][t] = s2; rv[3][t] = s3;
    ri[0][t] = code; ri[1][t] = code; ri[2][t] = code; ri[3][t] = code;
    __syncthreads();
    for (int s = 128; s > 0; s >>= 1) {
      if (t < s) {
#pragma unroll
        for (int qq = 0; qq < 4; ++qq)
          if (lexlt64(rv[qq][t + s], ri[qq][t + s], rv[qq][t], ri[qq][t])) {
            rv[qq][t] = rv[qq][t + s];
            ri[qq][t] = ri[qq][t + s];
          }
      }
      __syncthreads();
    }
    if (t == 0) {
#pragma unroll
      for (int qq = 0; qq < 4; ++qq) {
        const int mi = grp * 4 + qq;
        if (mi < cnt) {
          parv[mi * 16 + chunk] = rv[qq][0];
          parx[mi * 16 + chunk] = ri[qq][0];
        }
      }
    }
  }
}

// ---------------- K5: merge messy partials ----------------
__global__ __launch_bounds__(256) void vq_messy2(
    const int* __restrict__ messy, const int* __restrict__ messyCount,
    const double* __restrict__ parv, const int* __restrict__ parx,
    int* __restrict__ idxOut) {
  const int cnt0 = *messyCount;
  const int cnt = cnt0 > 4096 ? 4096 : cnt0;
  for (int j = blockIdx.x * 256 + threadIdx.x; j < cnt; j += gridDim.x * 256) {
    double bv = parv[j * 16];
    int bx = parx[j * 16];
    for (int ch = 1; ch < 16; ++ch) {
      const double v = parv[j * 16 + ch];
      const int x = parx[j * 16 + ch];
      if (lexlt64(v, x, bv, bx)) { bv = v; bx = x; }
    }
    idxOut[messy[j]] = bx;
  }
}

// ---------------- K6: row-gather z_q + loss + used marking (vectorized) ----------------
__global__ __launch_bounds__(256) void vq_out(
    const float* __restrict__ Z, const float* __restrict__ E,
    const int* __restrict__ idx, float* __restrict__ out,
    double* __restrict__ lossSum, int* __restrict__ used) {
  __shared__ float zt[32][257];   // stride 257: column reads 2-way alias (free)
  __shared__ int ids[32];
  const int tid = threadIdx.x;
  const int qb = blockIdx.x * 32;
  const int b = qb >> 10, hw0 = qb & 1023;
  if (tid < 32) {
    const int id = idx[qb + tid];
    ids[tid] = id;
    used[id] = 1;
  }
  __syncthreads();
  const int w = tid >> 6, l = tid & 63;
#pragma unroll
  for (int rr = 0; rr < 8; ++rr) {
    const int q = rr * 4 + w;
    const float4 v = *(const float4*)(E + (size_t)ids[q] * 256 + l * 4);
    zt[q][l * 4 + 0] = v.x;
    zt[q][l * 4 + 1] = v.y;
    zt[q][l * 4 + 2] = v.z;
    zt[q][l * 4 + 3] = v.w;
  }
  __syncthreads();
  const int h4 = (tid & 7) * 4;   // hw sub-offset (4-wide)
  const int c0 = tid >> 3;        // 32 c's per pass
  float ls = 0.f;
#pragma unroll
  for (int p = 0; p < 8; ++p) {
    const int c = p * 32 + c0;
    const size_t g = (size_t)b * 262144 + ((size_t)c << 10) + hw0 + h4;
    const float4 z4 = *(const float4*)(Z + g);
    float4 o;
    o.x = zt[h4 + 0][c];
    o.y = zt[h4 + 1][c];
    o.z = zt[h4 + 2][c];
    o.w = zt[h4 + 3][c];
    *(float4*)(out + g) = o;
    const float dx = o.x - z4.x, dy = o.y - z4.y;
    const float dz = o.z - z4.z, dw = o.w - z4.w;
    ls = fmaf(dx, dx, ls);
    ls = fmaf(dy, dy, ls);
    ls = fmaf(dz, dz, ls);
    ls = fmaf(dw, dw, ls);
  }
#pragma unroll
  for (int off = 32; off > 0; off >>= 1) ls += __shfl_down(ls, off);
  __shared__ float red[4];
  if (l == 0) red[w] = ls;
  __syncthreads();
  if (tid == 0)
    atomicAdd(lossSum, (double)((red[0] + red[1]) + (red[2] + red[3])));
}

// ---------------- K7: finalize scalars ----------------
__global__ __launch_bounds__(256) void vq_final(const int* __restrict__ used,
                                                const double* __restrict__ lossSum,
                                                float* __restrict__ out) {
  __shared__ int cnt[256];
  int c = 0;
  for (int k = threadIdx.x; k < 4096; k += 256) c += (used[k] > 0);
  cnt[threadIdx.x] = c;
  __syncthreads();
  if (threadIdx.x == 0) {
    int tot = 0;
    for (int t = 0; t < 256; ++t) tot += cnt[t];
    out[8388608] = (float)(*lossSum * 0.25 / 8388608.0);
    out[8388609] = (float)tot / 4096.0f;
  }
}

extern "C" void kernel_launch(void* const* d_in, const int* in_sizes, int n_in,
                              void* d_out, int out_size, void* d_ws, size_t ws_size,
                              hipStream_t stream) {
  const float* Z = (const float*)d_in[0];
  const float* E = (const float*)d_in[1];
  float* out = (float*)d_out;
  char* w = (char*)d_ws;

  int* idx = (int*)w;                          // 128 KB
  int* cand = (int*)(w + 131072);              // 128 KB
  float* en1024 = (float*)(w + 262144);        // 16 KB
  int* used = (int*)(w + 278528);              // 16 KB
  double* lossSum = (double*)(w + 294912);     // 8 B
  int* candCount = (int*)(w + 294920);         // 4 B
  int* messyCount = (int*)(w + 294924);        // 4 B

  // d_out doubles as scratch; all consumed before vq_out rewrites out.
  char* Epk16 = (char*)out;                    // 2 MB fp16 image  [0, 524288)
  int* pk0 = (int*)(out + 524288);             // 3 x 32768
  int* pk1 = (int*)(out + 655360);             // 3 x 32768
  int* pk2 = (int*)(out + 786432);             // 3 x 32768
  int* pi0 = (int*)(out + 917504);             // 32768
  int* pi1 = (int*)(out + 950272);             // 32768
  int* pi2 = (int*)(out + 983040);             // 32768
  int* messy = (int*)(out + 1015808);          // 4096
  double* parv = (double*)(out + 1019904);     // 4096 x 16 doubles
  int* parx = (int*)(out + 1150976);           // 4096 x 16 ints

  vq_prep<<<512, 256, 0, stream>>>(E, (uint4*)Epk16, en1024, used, lossSum,
                                   candCount, messyCount);
  vq_screen<<<768, 256, 0, stream>>>(Z, Epk16, en1024, pk0, pk1, pk2);
  vq_merge<<<128, 256, 0, stream>>>(pk0, pk1, pk2, idx, cand, candCount,
                                    messy, messyCount, pi0, pi1, pi2);
  vq_exact<<<768, 256, 0, stream>>>(Z, E, pi0, pi1, pi2, cand, candCount,
                                    messy, messyCount, parv, parx, idx);
  vq_messy2<<<8, 256, 0, stream>>>(messy, messyCount, parv, parx, idx);
  vq_out<<<1024, 256, 0, stream>>>(Z, E, idx, out, lossSum, used);
  vq_final<<<1, 256, 0, stream>>>(used, lossSum, out);
}

// Round 18
// 162.860 us; speedup vs baseline: 1.1414x; 1.1414x over previous
//
#include <hip/hip_runtime.h>
#include <math.h>

// VQ-VAE eval forward. z_e [32,256,32,32] fp32, E [4096,256] fp32.
// N = 32768 queries, K = 4096 codes, C = 256.
// Round 18 = RESTORE of round 15 (best verified: 161.76us total, screen 96us).
// Rounds 16 (wave-private LDS: bank-conflict period bug, 8.4M conflicts) and
// 17 (no-LDS direct-L2: latency-bound, all pipes <30%) both regressed; the
// 2-phase dbuf screen + med3 top-3 + enorm-C-init is the session optimum.
// Screen: 2 tiles/wave, 3 parts, grid 768 = 3 blocks/CU zero-tail, XCD
// swizzle. Packed-int top-3 keys, WGAP=52 window, fp64 cand3/messy anchor.

#define WGAP 52   // quantized-distance window (units of 1/1024)

using half8 = __attribute__((ext_vector_type(8))) _Float16;
using f32x4 = __attribute__((ext_vector_type(4))) float;

__device__ __forceinline__ void gload_lds16(const void* g, void* l) {
  __builtin_amdgcn_global_load_lds(
      (const __attribute__((address_space(1))) unsigned int*)g,
      (__attribute__((address_space(3))) unsigned int*)l, 16, 0, 0);
}

__device__ __forceinline__ bool lexlt64(double v, int x, double ov, int ox) {
  return (v < ov) || (v == ov && x < ox);
}

__device__ __forceinline__ int med3i(int a, int b, int c) {
  int d;
  asm("v_med3_i32 %0, %1, %2, %3" : "=v"(d) : "v"(a), "v"(b), "v"(c));
  return d;
}

// insert key into sorted triple (a0<=a1<=a2): 4 VALU ops via med3
__device__ __forceinline__ void ins3k(int key, int& a0, int& a1, int& a2) {
  const int n2 = min(a2, max(key, a1));
  const int n1 = med3i(key, a0, a1);
  a0 = min(key, a0);
  a1 = n1;
  a2 = n2;
}

// merge two sorted triples -> smallest 3 of union: 7 min/max ops
__device__ __forceinline__ void mrg3k(int& a0, int& a1, int& a2,
                                      int b0, int b1, int b2) {
  const int c0 = min(a0, b0);
  const int x = max(a0, b0);
  const int y = min(a1, b1);
  const int c1 = min(x, y);
  const int z = max(x, y);
  const int ww = min(a2, b2);
  const int c2 = min(z, ww);
  a0 = c0; a1 = c1; a2 = c2;
}

// ---------------- K1: E -> NEGATED fp16(x256) swizzled image + en32 ----------------
// Slice = 64 codes x 128 k = 16KB; g_slice = (code>>6)*2 + khalf (0..127).
// granule(16B) = g_slice*1024 + rc*16 + (jo ^ (rc&15)), rc = code&63.
// en32[code] = sum(e^2) * 32768 (C-init for the screen's MFMA).
// Also zeroes used[] and scalar accumulators (replay-safe).
__global__ __launch_bounds__(256) void vq_prep(const float* __restrict__ E,
                                               uint4* __restrict__ Epk,
                                               float* __restrict__ en32,
                                               int* __restrict__ used,
                                               double* __restrict__ lossSum,
                                               int* __restrict__ candCount,
                                               int* __restrict__ messyCount) {
  const int t = blockIdx.x * 256 + threadIdx.x;   // 131072 = 4096 codes x 32 octets
  if (t < 4096) used[t] = 0;
  if (t == 4096) *lossSum = 0.0;
  if (t == 4097) *candCount = 0;
  if (t == 4098) *messyCount = 0;
  const int code = t >> 5, j = t & 31;
  const int rc = code & 63;
  const int khalf = j >> 4, jo = j & 15;
  const float* src = E + (size_t)code * 256 + j * 8;
  const float4 v0 = *(const float4*)(src);
  const float4 v1 = *(const float4*)(src + 4);
  float zv[8] = {v0.x, v0.y, v0.z, v0.w, v1.x, v1.y, v1.z, v1.w};
  union { half8 h; uint4 u; } pk;
  float s = 0.f;
#pragma unroll
  for (int e = 0; e < 8; ++e) {
    const float z = zv[e];
    s = fmaf(z, z, s);
    pk.h[e] = (_Float16)(z * -256.0f);   // negated image
  }
  const size_t g = (size_t)((code >> 6) * 2 + khalf) * 1024 +
                   rc * 16 + (jo ^ (rc & 15));
  Epk[g] = pk.u;
#pragma unroll
  for (int off = 1; off < 32; off <<= 1) s += __shfl_xor(s, off);
  if (j == 0) en32[code] = s * 32768.0f;
}

// ---------------- K2: fp16 MFMA screen, packed-int top-3 ----------------
// grid 768 = 256 query-groups (128 q) x 3 code-parts (22/21/21 chunks of 64).
// 4 waves x 32 q (2 tiles); 16KB dbuf slices; exactly 3 blocks/CU, no tail.
// XCD swizzle: bid = (qg%8) + 8*(part + 3*(qg/8)) -> one qg per XCD.
// acc init = en32 (C-input); E negated -> acc_final = en*32768 - dot*65536.
__global__ __launch_bounds__(256, 3) void vq_screen(
    const float* __restrict__ Z, const char* __restrict__ Epk,
    const float* __restrict__ en32,
    int* __restrict__ pk0, int* __restrict__ pk1, int* __restrict__ pk2) {
  __shared__ char lds[32768];
  const int tid = threadIdx.x;
  const int w = tid >> 6, l = tid & 63;
  const int xcd = blockIdx.x & 7, inner = blockIdx.x >> 3;
  const int part = inner % 3;
  const int qg = (inner / 3) * 8 + xcd;
  const int chs = part * 21 + (part > 0 ? 1 : 0);     // {0, 22, 43}
  const int che = chs + (part == 0 ? 22 : 21);        // {22, 43, 64}
  const int qbase = qg * 128;
  const int b = qbase >> 10;
  const int hwq = (qbase & 1023) + w * 32 + (l & 15);

  // A-frags: fp16(z*256), 2 query-tiles x K=256
  const float* Zq = Z + (size_t)b * 262144 + hwq;
  half8 ah[2][8];
#pragma unroll
  for (int u = 0; u < 2; ++u)
#pragma unroll
    for (int ks = 0; ks < 8; ++ks) {
      const int c0 = ks * 32 + (l >> 4) * 8;
#pragma unroll
      for (int e = 0; e < 8; ++e)
        ah[u][ks][e] = (_Float16)(Zq[u * 16 + ((size_t)(c0 + e) << 10)] * 256.0f);
    }

  // swizzled LDS read offsets (within 4KB code-tile row block)
  int lo[4];
#pragma unroll
  for (int s = 0; s < 4; ++s)
    lo[s] = (l & 15) * 256 + (((s * 4 + (l >> 4)) ^ (l & 15)) << 4);

  int k0[2][4], k1[2][4], k2[2][4];
#pragma unroll
  for (int u = 0; u < 2; ++u)
#pragma unroll
    for (int r = 0; r < 4; ++r) {
      k0[u][r] = 0x7fffffff; k1[u][r] = 0x7fffffff; k2[u][r] = 0x7fffffff;
    }

  auto stage = [&](int sel, int ss) {
    const char* src = Epk + ((size_t)ss << 14) + w * 4096 + l * 16;
    char* dst = lds + sel * 16384 + w * 4096;   // linear dest (rule 21)
#pragma unroll
    for (int i = 0; i < 4; ++i) gload_lds16(src + i * 1024, dst + i * 1024);
  };
  stage(0, chs * 2);   // first slice (even -> parity 0)

  for (int ch = chs; ch < che; ++ch) {
    // C-init: acc = en32[code] (broadcast across the 4 query rows)
    const int cb = ch * 64;
    f32x4 acc[2][4];
#pragma unroll
    for (int t = 0; t < 4; ++t) {
      const float en = en32[cb + t * 16 + (l & 15)];
      acc[0][t] = (f32x4){en, en, en, en};
      acc[1][t] = (f32x4){en, en, en, en};
    }

#pragma unroll
    for (int sh = 0; sh < 2; ++sh) {
      const int ss = ch * 2 + sh;
      __syncthreads();                                    // current buffer ready
      if (ss + 1 < che * 2) stage((ss + 1) & 1, ss + 1);  // async prefetch next
      const char* Lb = lds + (ss & 1) * 16384;
      __builtin_amdgcn_s_setprio(1);
#pragma unroll
      for (int s = 0; s < 4; ++s) {
        const int ks = sh * 4 + s;
#pragma unroll
        for (int t = 0; t < 4; ++t) {
          const half8 eh = *(const half8*)(Lb + t * 4096 + lo[s]);
          acc[0][t] = __builtin_amdgcn_mfma_f32_16x16x32_f16(ah[0][ks], eh, acc[0][t], 0, 0, 0);
          acc[1][t] = __builtin_amdgcn_mfma_f32_16x16x32_f16(ah[1][ks], eh, acc[1][t], 0, 0, 0);
        }
      }
      __builtin_amdgcn_s_setprio(0);
    }

    // epilogue: d*1024 = acc * (1024/32768); pack key; 4-op insert
#pragma unroll
    for (int t = 0; t < 4; ++t) {
      const int code = cb + t * 16 + (l & 15);
#pragma unroll
      for (int u = 0; u < 2; ++u)
#pragma unroll
        for (int r = 0; r < 4; ++r) {
          const float df = acc[u][t][r] * 0.03125f;
          const int di = (int)df;                       // trunc: monotone
          const int key = (int)(((unsigned)di << 12) + (unsigned)code);
          ins3k(key, k0[u][r], k1[u][r], k2[u][r]);
        }
    }
  }

  // cross-lane top-3 merge over the 16 lanes sharing each row-group
#pragma unroll
  for (int mask = 1; mask <= 8; mask <<= 1) {
#pragma unroll
    for (int u = 0; u < 2; ++u)
#pragma unroll
      for (int r = 0; r < 4; ++r) {
        const int o0 = __shfl_xor(k0[u][r], mask);
        const int o1 = __shfl_xor(k1[u][r], mask);
        const int o2 = __shfl_xor(k2[u][r], mask);
        mrg3k(k0[u][r], k1[u][r], k2[u][r], o0, o1, o2);
      }
  }
  if ((l & 15) == 0) {
#pragma unroll
    for (int u = 0; u < 2; ++u)
#pragma unroll
      for (int r = 0; r < 4; ++r) {
        const int n = qbase + w * 32 + u * 16 + (l >> 4) * 4 + r;
        const int o = part * 32768 + n;
        pk0[o] = k0[u][r]; pk1[o] = k1[u][r]; pk2[o] = k2[u][r];
      }
  }
}

// ---------------- K3: merge 3 parts, classify ----------------
__global__ __launch_bounds__(256) void vq_merge(
    const int* __restrict__ pk0, const int* __restrict__ pk1,
    const int* __restrict__ pk2, int* __restrict__ idxOut,
    int* __restrict__ cand, int* __restrict__ candCount,
    int* __restrict__ messy, int* __restrict__ messyCount,
    int* __restrict__ pi0, int* __restrict__ pi1, int* __restrict__ pi2) {
  const int n = blockIdx.x * 256 + threadIdx.x;
  int a0 = pk0[n], a1 = pk1[n], a2 = pk2[n];
#pragma unroll
  for (int q = 1; q < 3; ++q) {
    const int o = q * 32768 + n;
    mrg3k(a0, a1, a2, pk0[o], pk1[o], pk2[o]);
  }
  const int x0 = a0 & 0xfff;
  idxOut[n] = x0;                       // final unless flagged
  const int d0 = a0 >> 12, d1 = a1 >> 12, d2 = a2 >> 12;
  if (d1 - d0 < WGAP) {
    if (d2 - d0 < WGAP) {
      const int p = atomicAdd(messyCount, 1);
      if (p < 4096) messy[p] = n;
    } else {
      const int p = atomicAdd(candCount, 1);
      cand[p] = n;
      pi0[n] = x0; pi1[n] = a1 & 0xfff; pi2[n] = a2 & 0xfff;
    }
  }
}

// ---------------- K4: fused exact resolution (block-range split, no fences) ----
// Blocks [0,256): fp64 3-way compare for cand queries (wave per query).
// Blocks [256,768): fp64 full-row partial argmin for messy queries.
__global__ __launch_bounds__(256) void vq_exact(
    const float* __restrict__ Z, const float* __restrict__ E,
    const int* __restrict__ pi0, const int* __restrict__ pi1,
    const int* __restrict__ pi2, const int* __restrict__ cand,
    const int* __restrict__ candCount, const int* __restrict__ messy,
    const int* __restrict__ messyCount, double* __restrict__ parv,
    int* __restrict__ parx, int* __restrict__ idxOut) {
  __shared__ float zs[4][256];
  __shared__ double rv[4][256];
  __shared__ int ri[4][256];
  const int t = threadIdx.x;
  const int w = t >> 6, l = t & 63;

  if (blockIdx.x < 256) {
    // ---- cand3: one wave per query, stride 1024 ----
    const int cnt = *candCount;
    for (int j = blockIdx.x * 4 + w; j < cnt; j += 1024) {
      const int n = cand[j];
      const int b = n >> 10, hw = n & 1023;
      const int ca = pi0[n], cbn = pi1[n], cc = pi2[n];
      float z4[4];
#pragma unroll
      for (int i = 0; i < 4; ++i)
        z4[i] = Z[(size_t)b * 262144 + ((size_t)(l * 4 + i) << 10) + hw];
      const float4 e0 = *(const float4*)(E + (size_t)ca * 256 + l * 4);
      const float4 e1 = *(const float4*)(E + (size_t)cbn * 256 + l * 4);
      const float4 e2 = *(const float4*)(E + (size_t)cc * 256 + l * 4);
      double d0 = 0, d1 = 0, d2 = 0;
      const float* p0 = (const float*)&e0;
      const float* p1 = (const float*)&e1;
      const float* p2 = (const float*)&e2;
#pragma unroll
      for (int i = 0; i < 4; ++i) {
        const double f0 = (double)z4[i] - (double)p0[i];
        const double f1 = (double)z4[i] - (double)p1[i];
        const double f2 = (double)z4[i] - (double)p2[i];
        d0 = fma(f0, f0, d0);
        d1 = fma(f1, f1, d1);
        d2 = fma(f2, f2, d2);
      }
#pragma unroll
      for (int off = 32; off > 0; off >>= 1) {
        d0 += __shfl_down(d0, off);
        d1 += __shfl_down(d1, off);
        d2 += __shfl_down(d2, off);
      }
      if (l == 0) {
        double bv = d0; int bx = ca;
        if (lexlt64(d1, cbn, bv, bx)) { bv = d1; bx = cbn; }
        if (lexlt64(d2, cc, bv, bx)) { bv = d2; bx = cc; }
        idxOut[n] = bx;
      }
    }
    return;
  }

  // ---- messy1: 512 blocks, chunked fp64 full-row partial argmin ----
  const int cnt0 = *messyCount;
  const int cnt = cnt0 > 4096 ? 4096 : cnt0;
  const int jobs = ((cnt + 3) >> 2) * 16;
  for (int job = blockIdx.x - 256; job < jobs; job += 512) {
    const int grp = job >> 4, chunk = job & 15;
    __syncthreads();
    {
      const int q = t >> 6, lq = t & 63;
      const int mi = grp * 4 + q;
      const int n = messy[mi < cnt ? mi : grp * 4];
      const int b = n >> 10, hw = n & 1023;
#pragma unroll
      for (int i = 0; i < 4; ++i)
        zs[q][lq * 4 + i] =
            Z[(size_t)b * 262144 + ((size_t)(lq * 4 + i) << 10) + hw];
    }
    __syncthreads();
    const int code = chunk * 256 + t;
    const float* er = E + (size_t)code * 256;
    double s0 = 0, s1 = 0, s2 = 0, s3 = 0;
    for (int c = 0; c < 256; ++c) {
      const double ec = (double)er[c];
      const double f0 = (double)zs[0][c] - ec;
      const double f1 = (double)zs[1][c] - ec;
      const double f2 = (double)zs[2][c] - ec;
      const double f3 = (double)zs[3][c] - ec;
      s0 = fma(f0, f0, s0);
      s1 = fma(f1, f1, s1);
      s2 = fma(f2, f2, s2);
      s3 = fma(f3, f3, s3);
    }
    rv[0][t] = s0; rv[1][t] = s1; rv[2][t] = s2; rv[3][t] = s3;
    ri[0][t] = code; ri[1][t] = code; ri[2][t] = code; ri[3][t] = code;
    __syncthreads();
    for (int s = 128; s > 0; s >>= 1) {
      if (t < s) {
#pragma unroll
        for (int qq = 0; qq < 4; ++qq)
          if (lexlt64(rv[qq][t + s], ri[qq][t + s], rv[qq][t], ri[qq][t])) {
            rv[qq][t] = rv[qq][t + s];
            ri[qq][t] = ri[qq][t + s];
          }
      }
      __syncthreads();
    }
    if (t == 0) {
#pragma unroll
      for (int qq = 0; qq < 4; ++qq) {
        const int mi = grp * 4 + qq;
        if (mi < cnt) {
          parv[mi * 16 + chunk] = rv[qq][0];
          parx[mi * 16 + chunk] = ri[qq][0];
        }
      }
    }
  }
}

// ---------------- K5: merge messy partials ----------------
__global__ __launch_bounds__(256) void vq_messy2(
    const int* __restrict__ messy, const int* __restrict__ messyCount,
    const double* __restrict__ parv, const int* __restrict__ parx,
    int* __restrict__ idxOut) {
  const int cnt0 = *messyCount;
  const int cnt = cnt0 > 4096 ? 4096 : cnt0;
  for (int j = blockIdx.x * 256 + threadIdx.x; j < cnt; j += gridDim.x * 256) {
    double bv = parv[j * 16];
    int bx = parx[j * 16];
    for (int ch = 1; ch < 16; ++ch) {
      const double v = parv[j * 16 + ch];
      const int x = parx[j * 16 + ch];
      if (lexlt64(v, x, bv, bx)) { bv = v; bx = x; }
    }
    idxOut[messy[j]] = bx;
  }
}

// ---------------- K6: row-gather z_q + loss + used marking (vectorized) ----------------
__global__ __launch_bounds__(256) void vq_out(
    const float* __restrict__ Z, const float* __restrict__ E,
    const int* __restrict__ idx, float* __restrict__ out,
    double* __restrict__ lossSum, int* __restrict__ used) {
  __shared__ float zt[32][257];   // stride 257: column reads 2-way alias (free)
  __shared__ int ids[32];
  const int tid = threadIdx.x;
  const int qb = blockIdx.x * 32;
  const int b = qb >> 10, hw0 = qb & 1023;
  if (tid < 32) {
    const int id = idx[qb + tid];
    ids[tid] = id;
    used[id] = 1;
  }
  __syncthreads();
  const int w = tid >> 6, l = tid & 63;
#pragma unroll
  for (int rr = 0; rr < 8; ++rr) {
    const int q = rr * 4 + w;
    const float4 v = *(const float4*)(E + (size_t)ids[q] * 256 + l * 4);
    zt[q][l * 4 + 0] = v.x;
    zt[q][l * 4 + 1] = v.y;
    zt[q][l * 4 + 2] = v.z;
    zt[q][l * 4 + 3] = v.w;
  }
  __syncthreads();
  const int h4 = (tid & 7) * 4;   // hw sub-offset (4-wide)
  const int c0 = tid >> 3;        // 32 c's per pass
  float ls = 0.f;
#pragma unroll
  for (int p = 0; p < 8; ++p) {
    const int c = p * 32 + c0;
    const size_t g = (size_t)b * 262144 + ((size_t)c << 10) + hw0 + h4;
    const float4 z4 = *(const float4*)(Z + g);
    float4 o;
    o.x = zt[h4 + 0][c];
    o.y = zt[h4 + 1][c];
    o.z = zt[h4 + 2][c];
    o.w = zt[h4 + 3][c];
    *(float4*)(out + g) = o;
    const float dx = o.x - z4.x, dy = o.y - z4.y;
    const float dz = o.z - z4.z, dw = o.w - z4.w;
    ls = fmaf(dx, dx, ls);
    ls = fmaf(dy, dy, ls);
    ls = fmaf(dz, dz, ls);
    ls = fmaf(dw, dw, ls);
  }
#pragma unroll
  for (int off = 32; off > 0; off >>= 1) ls += __shfl_down(ls, off);
  __shared__ float red[4];
  if (l == 0) red[w] = ls;
  __syncthreads();
  if (tid == 0)
    atomicAdd(lossSum, (double)((red[0] + red[1]) + (red[2] + red[3])));
}

// ---------------- K7: finalize scalars ----------------
__global__ __launch_bounds__(256) void vq_final(const int* __restrict__ used,
                                                const double* __restrict__ lossSum,
                                                float* __restrict__ out) {
  __shared__ int cnt[256];
  int c = 0;
  for (int k = threadIdx.x; k < 4096; k += 256) c += (used[k] > 0);
  cnt[threadIdx.x] = c;
  __syncthreads();
  if (threadIdx.x == 0) {
    int tot = 0;
    for (int t = 0; t < 256; ++t) tot += cnt[t];
    out[8388608] = (float)(*lossSum * 0.25 / 8388608.0);
    out[8388609] = (float)tot / 4096.0f;
  }
}

extern "C" void kernel_launch(void* const* d_in, const int* in_sizes, int n_in,
                              void* d_out, int out_size, void* d_ws, size_t ws_size,
                              hipStream_t stream) {
  const float* Z = (const float*)d_in[0];
  const float* E = (const float*)d_in[1];
  float* out = (float*)d_out;
  char* w = (char*)d_ws;

  int* idx = (int*)w;                          // 128 KB
  int* cand = (int*)(w + 131072);              // 128 KB
  float* en32 = (float*)(w + 262144);          // 16 KB
  int* used = (int*)(w + 278528);              // 16 KB
  double* lossSum = (double*)(w + 294912);     // 8 B
  int* candCount = (int*)(w + 294920);         // 4 B
  int* messyCount = (int*)(w + 294924);        // 4 B

  // d_out doubles as scratch; all consumed before vq_out rewrites out.
  char* Epk16 = (char*)out;                    // 2 MB fp16 image  [0, 524288)
  int* pk0 = (int*)(out + 524288);             // 3 x 32768
  int* pk1 = (int*)(out + 655360);             // 3 x 32768
  int* pk2 = (int*)(out + 786432);             // 3 x 32768
  int* pi0 = (int*)(out + 917504);             // 32768
  int* pi1 = (int*)(out + 950272);             // 32768
  int* pi2 = (int*)(out + 983040);             // 32768
  int* messy = (int*)(out + 1015808);          // 4096
  double* parv = (double*)(out + 1019904);     // 4096 x 16 doubles
  int* parx = (int*)(out + 1150976);           // 4096 x 16 ints

  vq_prep<<<512, 256, 0, stream>>>(E, (uint4*)Epk16, en32, used, lossSum,
                                   candCount, messyCount);
  vq_screen<<<768, 256, 0, stream>>>(Z, Epk16, en32, pk0, pk1, pk2);
  vq_merge<<<128, 256, 0, stream>>>(pk0, pk1, pk2, idx, cand, candCount,
                                    messy, messyCount, pi0, pi1, pi2);
  vq_exact<<<768, 256, 0, stream>>>(Z, E, pi0, pi1, pi2, cand, candCount,
                                    messy, messyCount, parv, parx, idx);
  vq_messy2<<<8, 256, 0, stream>>>(messy, messyCount, parv, parx, idx);
  vq_out<<<1024, 256, 0, stream>>>(Z, E, idx, out, lossSum, used);
  vq_final<<<1, 256, 0, stream>>>(used, lossSum, out);
}

// Round 19
// 160.920 us; speedup vs baseline: 1.1552x; 1.0121x over previous
//
#include <hip/hip_runtime.h>
#include <math.h>

// VQ-VAE eval forward. z_e [32,256,32,32] fp32, E [4096,256] fp32.
// N = 32768 queries, K = 4096 codes, C = 256.
// Round 19 = round 18 (restored optimum, 162.9us) + ONE change: A-scale 8.
//   A = fp16(z*8) (power-of-2 scale: identical fp16 rounding to z*256,
//   HW-verified in rounds 16/17), C-init = en*1024 -> acc = d*1024 directly;
//   epilogue drops the *0.03125 multiply (32 VALU ops/chunk/thread off the
//   binding VALU pipe).
// Screen: 2 tiles/wave, 3 parts, grid 768 = 3 blocks/CU zero-tail, XCD
// swizzle, med3 top-3. Packed-int keys, WGAP=52, fp64 cand3/messy anchor.

#define WGAP 52   // quantized-distance window (units of 1/1024)

using half8 = __attribute__((ext_vector_type(8))) _Float16;
using f32x4 = __attribute__((ext_vector_type(4))) float;

__device__ __forceinline__ void gload_lds16(const void* g, void* l) {
  __builtin_amdgcn_global_load_lds(
      (const __attribute__((address_space(1))) unsigned int*)g,
      (__attribute__((address_space(3))) unsigned int*)l, 16, 0, 0);
}

__device__ __forceinline__ bool lexlt64(double v, int x, double ov, int ox) {
  return (v < ov) || (v == ov && x < ox);
}

__device__ __forceinline__ int med3i(int a, int b, int c) {
  int d;
  asm("v_med3_i32 %0, %1, %2, %3" : "=v"(d) : "v"(a), "v"(b), "v"(c));
  return d;
}

// insert key into sorted triple (a0<=a1<=a2): 4 VALU ops via med3
__device__ __forceinline__ void ins3k(int key, int& a0, int& a1, int& a2) {
  const int n2 = min(a2, max(key, a1));
  const int n1 = med3i(key, a0, a1);
  a0 = min(key, a0);
  a1 = n1;
  a2 = n2;
}

// merge two sorted triples -> smallest 3 of union: 7 min/max ops
__device__ __forceinline__ void mrg3k(int& a0, int& a1, int& a2,
                                      int b0, int b1, int b2) {
  const int c0 = min(a0, b0);
  const int x = max(a0, b0);
  const int y = min(a1, b1);
  const int c1 = min(x, y);
  const int z = max(x, y);
  const int ww = min(a2, b2);
  const int c2 = min(z, ww);
  a0 = c0; a1 = c1; a2 = c2;
}

// ---------------- K1: E -> NEGATED fp16(x256) swizzled image + enorm*1024 ----------------
// Slice = 64 codes x 128 k = 16KB; g_slice = (code>>6)*2 + khalf (0..127).
// granule(16B) = g_slice*1024 + rc*16 + (jo ^ (rc&15)), rc = code&63.
// en1024[code] = sum(e^2) * 1024 (C-init; A-scale 8 * B-scale 256 = 2048).
// Also zeroes used[] and scalar accumulators (replay-safe).
__global__ __launch_bounds__(256) void vq_prep(const float* __restrict__ E,
                                               uint4* __restrict__ Epk,
                                               float* __restrict__ en1024,
                                               int* __restrict__ used,
                                               double* __restrict__ lossSum,
                                               int* __restrict__ candCount,
                                               int* __restrict__ messyCount) {
  const int t = blockIdx.x * 256 + threadIdx.x;   // 131072 = 4096 codes x 32 octets
  if (t < 4096) used[t] = 0;
  if (t == 4096) *lossSum = 0.0;
  if (t == 4097) *candCount = 0;
  if (t == 4098) *messyCount = 0;
  const int code = t >> 5, j = t & 31;
  const int rc = code & 63;
  const int khalf = j >> 4, jo = j & 15;
  const float* src = E + (size_t)code * 256 + j * 8;
  const float4 v0 = *(const float4*)(src);
  const float4 v1 = *(const float4*)(src + 4);
  float zv[8] = {v0.x, v0.y, v0.z, v0.w, v1.x, v1.y, v1.z, v1.w};
  union { half8 h; uint4 u; } pk;
  float s = 0.f;
#pragma unroll
  for (int e = 0; e < 8; ++e) {
    const float z = zv[e];
    s = fmaf(z, z, s);
    pk.h[e] = (_Float16)(z * -256.0f);   // negated image
  }
  const size_t g = (size_t)((code >> 6) * 2 + khalf) * 1024 +
                   rc * 16 + (jo ^ (rc & 15));
  Epk[g] = pk.u;
#pragma unroll
  for (int off = 1; off < 32; off <<= 1) s += __shfl_xor(s, off);
  if (j == 0) en1024[code] = s * 1024.0f;
}

// ---------------- K2: fp16 MFMA screen, packed-int top-3 ----------------
// grid 768 = 256 query-groups (128 q) x 3 code-parts (22/21/21 chunks of 64).
// 4 waves x 32 q (2 tiles); 16KB dbuf slices; exactly 3 blocks/CU, no tail.
// XCD swizzle: bid = (qg%8) + 8*(part + 3*(qg/8)) -> one qg per XCD.
// A = fp16(z*8), B = fp16(-e*256), C-init = en*1024 -> acc = d*1024 direct.
__global__ __launch_bounds__(256, 3) void vq_screen(
    const float* __restrict__ Z, const char* __restrict__ Epk,
    const float* __restrict__ en1024,
    int* __restrict__ pk0, int* __restrict__ pk1, int* __restrict__ pk2) {
  __shared__ char lds[32768];
  const int tid = threadIdx.x;
  const int w = tid >> 6, l = tid & 63;
  const int xcd = blockIdx.x & 7, inner = blockIdx.x >> 3;
  const int part = inner % 3;
  const int qg = (inner / 3) * 8 + xcd;
  const int chs = part * 21 + (part > 0 ? 1 : 0);     // {0, 22, 43}
  const int che = chs + (part == 0 ? 22 : 21);        // {22, 43, 64}
  const int qbase = qg * 128;
  const int b = qbase >> 10;
  const int hwq = (qbase & 1023) + w * 32 + (l & 15);

  // A-frags: fp16(z*8), 2 query-tiles x K=256
  const float* Zq = Z + (size_t)b * 262144 + hwq;
  half8 ah[2][8];
#pragma unroll
  for (int u = 0; u < 2; ++u)
#pragma unroll
    for (int ks = 0; ks < 8; ++ks) {
      const int c0 = ks * 32 + (l >> 4) * 8;
#pragma unroll
      for (int e = 0; e < 8; ++e)
        ah[u][ks][e] = (_Float16)(Zq[u * 16 + ((size_t)(c0 + e) << 10)] * 8.0f);
    }

  // swizzled LDS read offsets (within 4KB code-tile row block)
  int lo[4];
#pragma unroll
  for (int s = 0; s < 4; ++s)
    lo[s] = (l & 15) * 256 + (((s * 4 + (l >> 4)) ^ (l & 15)) << 4);

  int k0[2][4], k1[2][4], k2[2][4];
#pragma unroll
  for (int u = 0; u < 2; ++u)
#pragma unroll
    for (int r = 0; r < 4; ++r) {
      k0[u][r] = 0x7fffffff; k1[u][r] = 0x7fffffff; k2[u][r] = 0x7fffffff;
    }

  auto stage = [&](int sel, int ss) {
    const char* src = Epk + ((size_t)ss << 14) + w * 4096 + l * 16;
    char* dst = lds + sel * 16384 + w * 4096;   // linear dest (rule 21)
#pragma unroll
    for (int i = 0; i < 4; ++i) gload_lds16(src + i * 1024, dst + i * 1024);
  };
  stage(0, chs * 2);   // first slice (even -> parity 0)

  for (int ch = chs; ch < che; ++ch) {
    // C-init: acc = en1024[code] (broadcast across the 4 query rows)
    const int cb = ch * 64;
    f32x4 acc[2][4];
#pragma unroll
    for (int t = 0; t < 4; ++t) {
      const float en = en1024[cb + t * 16 + (l & 15)];
      acc[0][t] = (f32x4){en, en, en, en};
      acc[1][t] = (f32x4){en, en, en, en};
    }

#pragma unroll
    for (int sh = 0; sh < 2; ++sh) {
      const int ss = ch * 2 + sh;
      __syncthreads();                                    // current buffer ready
      if (ss + 1 < che * 2) stage((ss + 1) & 1, ss + 1);  // async prefetch next
      const char* Lb = lds + (ss & 1) * 16384;
      __builtin_amdgcn_s_setprio(1);
#pragma unroll
      for (int s = 0; s < 4; ++s) {
        const int ks = sh * 4 + s;
#pragma unroll
        for (int t = 0; t < 4; ++t) {
          const half8 eh = *(const half8*)(Lb + t * 4096 + lo[s]);
          acc[0][t] = __builtin_amdgcn_mfma_f32_16x16x32_f16(ah[0][ks], eh, acc[0][t], 0, 0, 0);
          acc[1][t] = __builtin_amdgcn_mfma_f32_16x16x32_f16(ah[1][ks], eh, acc[1][t], 0, 0, 0);
        }
      }
      __builtin_amdgcn_s_setprio(0);
    }

    // epilogue: acc IS d*1024; pack key; 4-op insert
#pragma unroll
    for (int t = 0; t < 4; ++t) {
      const int code = cb + t * 16 + (l & 15);
#pragma unroll
      for (int u = 0; u < 2; ++u)
#pragma unroll
        for (int r = 0; r < 4; ++r) {
          const int di = (int)acc[u][t][r];             // trunc: monotone
          const int key = (int)(((unsigned)di << 12) + (unsigned)code);
          ins3k(key, k0[u][r], k1[u][r], k2[u][r]);
        }
    }
  }

  // cross-lane top-3 merge over the 16 lanes sharing each row-group
#pragma unroll
  for (int mask = 1; mask <= 8; mask <<= 1) {
#pragma unroll
    for (int u = 0; u < 2; ++u)
#pragma unroll
      for (int r = 0; r < 4; ++r) {
        const int o0 = __shfl_xor(k0[u][r], mask);
        const int o1 = __shfl_xor(k1[u][r], mask);
        const int o2 = __shfl_xor(k2[u][r], mask);
        mrg3k(k0[u][r], k1[u][r], k2[u][r], o0, o1, o2);
      }
  }
  if ((l & 15) == 0) {
#pragma unroll
    for (int u = 0; u < 2; ++u)
#pragma unroll
      for (int r = 0; r < 4; ++r) {
        const int n = qbase + w * 32 + u * 16 + (l >> 4) * 4 + r;
        const int o = part * 32768 + n;
        pk0[o] = k0[u][r]; pk1[o] = k1[u][r]; pk2[o] = k2[u][r];
      }
  }
}

// ---------------- K3: merge 3 parts, classify ----------------
__global__ __launch_bounds__(256) void vq_merge(
    const int* __restrict__ pk0, const int* __restrict__ pk1,
    const int* __restrict__ pk2, int* __restrict__ idxOut,
    int* __restrict__ cand, int* __restrict__ candCount,
    int* __restrict__ messy, int* __restrict__ messyCount,
    int* __restrict__ pi0, int* __restrict__ pi1, int* __restrict__ pi2) {
  const int n = blockIdx.x * 256 + threadIdx.x;
  int a0 = pk0[n], a1 = pk1[n], a2 = pk2[n];
#pragma unroll
  for (int q = 1; q < 3; ++q) {
    const int o = q * 32768 + n;
    mrg3k(a0, a1, a2, pk0[o], pk1[o], pk2[o]);
  }
  const int x0 = a0 & 0xfff;
  idxOut[n] = x0;                       // final unless flagged
  const int d0 = a0 >> 12, d1 = a1 >> 12, d2 = a2 >> 12;
  if (d1 - d0 < WGAP) {
    if (d2 - d0 < WGAP) {
      const int p = atomicAdd(messyCount, 1);
      if (p < 4096) messy[p] = n;
    } else {
      const int p = atomicAdd(candCount, 1);
      cand[p] = n;
      pi0[n] = x0; pi1[n] = a1 & 0xfff; pi2[n] = a2 & 0xfff;
    }
  }
}

// ---------------- K4: fused exact resolution (block-range split, no fences) ----
// Blocks [0,256): fp64 3-way compare for cand queries (wave per query).
// Blocks [256,768): fp64 full-row partial argmin for messy queries.
__global__ __launch_bounds__(256) void vq_exact(
    const float* __restrict__ Z, const float* __restrict__ E,
    const int* __restrict__ pi0, const int* __restrict__ pi1,
    const int* __restrict__ pi2, const int* __restrict__ cand,
    const int* __restrict__ candCount, const int* __restrict__ messy,
    const int* __restrict__ messyCount, double* __restrict__ parv,
    int* __restrict__ parx, int* __restrict__ idxOut) {
  __shared__ float zs[4][256];
  __shared__ double rv[4][256];
  __shared__ int ri[4][256];
  const int t = threadIdx.x;
  const int w = t >> 6, l = t & 63;

  if (blockIdx.x < 256) {
    // ---- cand3: one wave per query, stride 1024 ----
    const int cnt = *candCount;
    for (int j = blockIdx.x * 4 + w; j < cnt; j += 1024) {
      const int n = cand[j];
      const int b = n >> 10, hw = n & 1023;
      const int ca = pi0[n], cbn = pi1[n], cc = pi2[n];
      float z4[4];
#pragma unroll
      for (int i = 0; i < 4; ++i)
        z4[i] = Z[(size_t)b * 262144 + ((size_t)(l * 4 + i) << 10) + hw];
      const float4 e0 = *(const float4*)(E + (size_t)ca * 256 + l * 4);
      const float4 e1 = *(const float4*)(E + (size_t)cbn * 256 + l * 4);
      const float4 e2 = *(const float4*)(E + (size_t)cc * 256 + l * 4);
      double d0 = 0, d1 = 0, d2 = 0;
      const float* p0 = (const float*)&e0;
      const float* p1 = (const float*)&e1;
      const float* p2 = (const float*)&e2;
#pragma unroll
      for (int i = 0; i < 4; ++i) {
        const double f0 = (double)z4[i] - (double)p0[i];
        const double f1 = (double)z4[i] - (double)p1[i];
        const double f2 = (double)z4[i] - (double)p2[i];
        d0 = fma(f0, f0, d0);
        d1 = fma(f1, f1, d1);
        d2 = fma(f2, f2, d2);
      }
#pragma unroll
      for (int off = 32; off > 0; off >>= 1) {
        d0 += __shfl_down(d0, off);
        d1 += __shfl_down(d1, off);
        d2 += __shfl_down(d2, off);
      }
      if (l == 0) {
        double bv = d0; int bx = ca;
        if (lexlt64(d1, cbn, bv, bx)) { bv = d1; bx = cbn; }
        if (lexlt64(d2, cc, bv, bx)) { bv = d2; bx = cc; }
        idxOut[n] = bx;
      }
    }
    return;
  }

  // ---- messy1: 512 blocks, chunked fp64 full-row partial argmin ----
  const int cnt0 = *messyCount;
  const int cnt = cnt0 > 4096 ? 4096 : cnt0;
  const int jobs = ((cnt + 3) >> 2) * 16;
  for (int job = blockIdx.x - 256; job < jobs; job += 512) {
    const int grp = job >> 4, chunk = job & 15;
    __syncthreads();
    {
      const int q = t >> 6, lq = t & 63;
      const int mi = grp * 4 + q;
      const int n = messy[mi < cnt ? mi : grp * 4];
      const int b = n >> 10, hw = n & 1023;
#pragma unroll
      for (int i = 0; i < 4; ++i)
        zs[q][lq * 4 + i] =
            Z[(size_t)b * 262144 + ((size_t)(lq * 4 + i) << 10) + hw];
    }
    __syncthreads();
    const int code = chunk * 256 + t;
    const float* er = E + (size_t)code * 256;
    double s0 = 0, s1 = 0, s2 = 0, s3 = 0;
    for (int c = 0; c < 256; ++c) {
      const double ec = (double)er[c];
      const double f0 = (double)zs[0][c] - ec;
      const double f1 = (double)zs[1][c] - ec;
      const double f2 = (double)zs[2][c] - ec;
      const double f3 = (double)zs[3][c] - ec;
      s0 = fma(f0, f0, s0);
      s1 = fma(f1, f1, s1);
      s2 = fma(f2, f2, s2);
      s3 = fma(f3, f3, s3);
    }
    rv[0][t] = s0; rv[1][t] = s1; rv[2][t] = s2; rv[3][t] = s3;
    ri[0][t] = code; ri[1][t] = code; ri[2][t] = code; ri[3][t] = code;
    __syncthreads();
    for (int s = 128; s > 0; s >>= 1) {
      if (t < s) {
#pragma unroll
        for (int qq = 0; qq < 4; ++qq)
          if (lexlt64(rv[qq][t + s], ri[qq][t + s], rv[qq][t], ri[qq][t])) {
            rv[qq][t] = rv[qq][t + s];
            ri[qq][t] = ri[qq][t + s];
          }
      }
      __syncthreads();
    }
    if (t == 0) {
#pragma unroll
      for (int qq = 0; qq < 4; ++qq) {
        const int mi = grp * 4 + qq;
        if (mi < cnt) {
          parv[mi * 16 + chunk] = rv[qq][0];
          parx[mi * 16 + chunk] = ri[qq][0];
        }
      }
    }
  }
}

// ---------------- K5: merge messy partials ----------------
__global__ __launch_bounds__(256) void vq_messy2(
    const int* __restrict__ messy, const int* __restrict__ messyCount,
    const double* __restrict__ parv, const int* __restrict__ parx,
    int* __restrict__ idxOut) {
  const int cnt0 = *messyCount;
  const int cnt = cnt0 > 4096 ? 4096 : cnt0;
  for (int j = blockIdx.x * 256 + threadIdx.x; j < cnt; j += gridDim.x * 256) {
    double bv = parv[j * 16];
    int bx = parx[j * 16];
    for (int ch = 1; ch < 16; ++ch) {
      const double v = parv[j * 16 + ch];
      const int x = parx[j * 16 + ch];
      if (lexlt64(v, x, bv, bx)) { bv = v; bx = x; }
    }
    idxOut[messy[j]] = bx;
  }
}

// ---------------- K6: row-gather z_q + loss + used marking (vectorized) ----------------
__global__ __launch_bounds__(256) void vq_out(
    const float* __restrict__ Z, const float* __restrict__ E,
    const int* __restrict__ idx, float* __restrict__ out,
    double* __restrict__ lossSum, int* __restrict__ used) {
  __shared__ float zt[32][257];   // stride 257: column reads 2-way alias (free)
  __shared__ int ids[32];
  const int tid = threadIdx.x;
  const int qb = blockIdx.x * 32;
  const int b = qb >> 10, hw0 = qb & 1023;
  if (tid < 32) {
    const int id = idx[qb + tid];
    ids[tid] = id;
    used[id] = 1;
  }
  __syncthreads();
  const int w = tid >> 6, l = tid & 63;
#pragma unroll
  for (int rr = 0; rr < 8; ++rr) {
    const int q = rr * 4 + w;
    const float4 v = *(const float4*)(E + (size_t)ids[q] * 256 + l * 4);
    zt[q][l * 4 + 0] = v.x;
    zt[q][l * 4 + 1] = v.y;
    zt[q][l * 4 + 2] = v.z;
    zt[q][l * 4 + 3] = v.w;
  }
  __syncthreads();
  const int h4 = (tid & 7) * 4;   // hw sub-offset (4-wide)
  const int c0 = tid >> 3;        // 32 c's per pass
  float ls = 0.f;
#pragma unroll
  for (int p = 0; p < 8; ++p) {
    const int c = p * 32 + c0;
    const size_t g = (size_t)b * 262144 + ((size_t)c << 10) + hw0 + h4;
    const float4 z4 = *(const float4*)(Z + g);
    float4 o;
    o.x = zt[h4 + 0][c];
    o.y = zt[h4 + 1][c];
    o.z = zt[h4 + 2][c];
    o.w = zt[h4 + 3][c];
    *(float4*)(out + g) = o;
    const float dx = o.x - z4.x, dy = o.y - z4.y;
    const float dz = o.z - z4.z, dw = o.w - z4.w;
    ls = fmaf(dx, dx, ls);
    ls = fmaf(dy, dy, ls);
    ls = fmaf(dz, dz, ls);
    ls = fmaf(dw, dw, ls);
  }
#pragma unroll
  for (int off = 32; off > 0; off >>= 1) ls += __shfl_down(ls, off);
  __shared__ float red[4];
  if (l == 0) red[w] = ls;
  __syncthreads();
  if (tid == 0)
    atomicAdd(lossSum, (double)((red[0] + red[1]) + (red[2] + red[3])));
}

// ---------------- K7: finalize scalars ----------------
__global__ __launch_bounds__(256) void vq_final(const int* __restrict__ used,
                                                const double* __restrict__ lossSum,
                                                float* __restrict__ out) {
  __shared__ int cnt[256];
  int c = 0;
  for (int k = threadIdx.x; k < 4096; k += 256) c += (used[k] > 0);
  cnt[threadIdx.x] = c;
  __syncthreads();
  if (threadIdx.x == 0) {
    int tot = 0;
    for (int t = 0; t < 256; ++t) tot += cnt[t];
    out[8388608] = (float)(*lossSum * 0.25 / 8388608.0);
    out[8388609] = (float)tot / 4096.0f;
  }
}

extern "C" void kernel_launch(void* const* d_in, const int* in_sizes, int n_in,
                              void* d_out, int out_size, void* d_ws, size_t ws_size,
                              hipStream_t stream) {
  const float* Z = (const float*)d_in[0];
  const float* E = (const float*)d_in[1];
  float* out = (float*)d_out;
  char* w = (char*)d_ws;

  int* idx = (int*)w;                          // 128 KB
  int* cand = (int*)(w + 131072);              // 128 KB
  float* en1024 = (float*)(w + 262144);        // 16 KB
  int* used = (int*)(w + 278528);              // 16 KB
  double* lossSum = (double*)(w + 294912);     // 8 B
  int* candCount = (int*)(w + 294920);         // 4 B
  int* messyCount = (int*)(w + 294924);        // 4 B

  // d_out doubles as scratch; all consumed before vq_out rewrites out.
  char* Epk16 = (char*)out;                    // 2 MB fp16 image  [0, 524288)
  int* pk0 = (int*)(out + 524288);             // 3 x 32768
  int* pk1 = (int*)(out + 655360);             // 3 x 32768
  int* pk2 = (int*)(out + 786432);             // 3 x 32768
  int* pi0 = (int*)(out + 917504);             // 32768
  int* pi1 = (int*)(out + 950272);             // 32768
  int* pi2 = (int*)(out + 983040);             // 32768
  int* messy = (int*)(out + 1015808);          // 4096
  double* parv = (double*)(out + 1019904);     // 4096 x 16 doubles
  int* parx = (int*)(out + 1150976);           // 4096 x 16 ints

  vq_prep<<<512, 256, 0, stream>>>(E, (uint4*)Epk16, en1024, used, lossSum,
                                   candCount, messyCount);
  vq_screen<<<768, 256, 0, stream>>>(Z, Epk16, en1024, pk0, pk1, pk2);
  vq_merge<<<128, 256, 0, stream>>>(pk0, pk1, pk2, idx, cand, candCount,
                                    messy, messyCount, pi0, pi1, pi2);
  vq_exact<<<768, 256, 0, stream>>>(Z, E, pi0, pi1, pi2, cand, candCount,
                                    messy, messyCount, parv, parx, idx);
  vq_messy2<<<8, 256, 0, stream>>>(messy, messyCount, parv, parx, idx);
  vq_out<<<1024, 256, 0, stream>>>(Z, E, idx, out, lossSum, used);
  vq_final<<<1, 256, 0, stream>>>(used, lossSum, out);
}